// Round 5
// baseline (5601.189 us; speedup 1.0000x reference)
//
#include <hip/hip_runtime.h>

// 2-layer LSTM (B=256,T=512,D=64,H=512) + FC(last step), MI355X gfx950.
// Round 13: R8 structure (proven: 2-barrier L0 / 3-barrier L1, wave-0-only
// polls, agent-scope IF$ protocol) + IF$-RESIDENT h0 RING:
//   - h0: 8-slot ring (2MB, hot in IF$) replaces 128MB write-once history.
//     Producer stores hit resident lines -> fast vmcnt(0) ack before flag.
//     Prewarm deleted (no cold write-allocate to hide; R8's prewarm also
//     delayed wave 0's poll by an HBM fetch via shared vmcnt).
//   - h0 consumers use the SAME agent-scope ldx8 loads R8 proved on the
//     ring-reused h1 buffer (IF$ coherence point; reuse-safe). Loads are
//     hoisted into arrays before the MFMA blocks to batch under one drain.
//   - New slot-reuse edge: L0 step it polls f1(G=g>>1 ring) >= it-7
//     (slot it&7 holds h0[it-8], consumed by L1 at step it-7). L0-peer
//     consumption implied by f0 >= it. Slack-7, acyclic, hang-free.
//   R12 lesson kept: polls stay wave-0-only (poll concurrency = IF$
//   contention). No new memory primitives, no new inline asm.

#define BATCH 256
#define SEQ   512
#define DIN   64
#define HID   512

typedef _Float16 f16_t;
typedef __attribute__((ext_vector_type(8))) _Float16 f16x8;
typedef __attribute__((ext_vector_type(4))) float    f32x4;

#define SCOPE_AGT __HIP_MEMORY_SCOPE_AGENT

__device__ inline f16x8 cvt8(const float* __restrict__ p) {
    f16x8 r;
#pragma unroll
    for (int j = 0; j < 8; j++) r[j] = (_Float16)p[j];
    return r;
}

__device__ inline f16x8 cvt8v(f32x4 lo, f32x4 hi) {
    f16x8 r;
#pragma unroll
    for (int j = 0; j < 4; j++) { r[j] = (_Float16)lo[j]; r[4 + j] = (_Float16)hi[j]; }
    return r;
}

// 16B coherence-point load (ring slots; bypasses L1/L2 -> never stale).
__device__ inline f16x8 ldx8(const f16_t* p) {
    const unsigned long long* q = (const unsigned long long*)p;
    unsigned long long a = __hip_atomic_load(q,     __ATOMIC_RELAXED, SCOPE_AGT);
    unsigned long long b = __hip_atomic_load(q + 1, __ATOMIC_RELAXED, SCOPE_AGT);
    union { unsigned long long u[2]; f16x8 v; } c;
    c.u[0] = a; c.u[1] = b;
    return c.v;
}

// Coherent h-pair store (dword to IF$).
__device__ inline void sth2a(f16_t* base_even, float h, float hn) {
    union { struct { _Float16 lo, hi; } s; unsigned u; } pk;
    pk.s.lo = (_Float16)h; pk.s.hi = (_Float16)hn;
    __hip_atomic_store((unsigned*)base_even, pk.u, __ATOMIC_RELAXED, SCOPE_AGT);
}

__device__ inline float sgm(float v) { return 1.f / (1.f + __expf(-v)); }
__device__ inline float th(float v)  { return 1.f - 2.f / (__expf(2.f * v) + 1.f); }

__global__ __launch_bounds__(256, 1) void lstm_pipe(
    const float* __restrict__ x,
    const float* __restrict__ wih0, const float* __restrict__ whh0,
    const float* __restrict__ bih0, const float* __restrict__ bhh0,
    const float* __restrict__ wih1, const float* __restrict__ whh1,
    const float* __restrict__ bih1, const float* __restrict__ bhh1,
    unsigned* __restrict__ f0m, unsigned* __restrict__ f1,
    f16_t* __restrict__ h1buf, f16_t* __restrict__ h0ring)
{
    // 87 KB: 2 blocks would need 174 KB > 160 KB -> guaranteed 1 block/CU.
    __shared__ f32x4 red[5][17][64];     // use [0..3][0..15][lane]

    const int tid  = threadIdx.x;
    const int w    = tid >> 6, lane = tid & 63;
    const int quad = lane >> 4, col = lane & 15;
    const int bid  = blockIdx.x;

    if (bid < 128) {
        // ============ L0 block: (g, s) -- 32 rows x 32 dims ============
        const int g = bid & 7, s = bid >> 3;           // s < 16
        unsigned* myf = f0m + g * 64;                  // flags [s*4+m*2+ct], val it+1
        const int mym = w & 1, myct = w >> 1;          // this wave's cell quarter
        // slot-reuse backpressure: L1 group G=g>>1's ring must reach it-7
        const unsigned* bp = f1 + (size_t)(g >> 1) * 32 + (lane & 31);

        f16x8 Wh[32];                                  // [i<4][ct<2][nt<4]
#pragma unroll
        for (int i = 0; i < 4; i++) {
            const int k0 = (w * 4 + i) * 32 + quad * 8;
#pragma unroll
            for (int ct = 0; ct < 2; ct++)
#pragma unroll
                for (int nt = 0; nt < 4; nt++) {
                    const int gr = nt * HID + s * 32 + ct * 16 + col;
                    Wh[i * 8 + ct * 4 + nt] = cvt8(whh0 + (size_t)gr * HID + k0);
                }
        }
        f16x8 Wx[8];
        if (w >= 2) {
#pragma unroll
            for (int ct = 0; ct < 2; ct++)
#pragma unroll
                for (int nt = 0; nt < 4; nt++) {
                    const int gr = nt * HID + s * 32 + ct * 16 + col;
                    Wx[ct * 4 + nt] = cvt8(wih0 + (size_t)gr * DIN + (w - 2) * 32 + quad * 8);
                }
        } else {
#pragma unroll
            for (int j = 0; j < 8; j++) Wx[j] = (f16x8)(_Float16)0;
        }
#pragma unroll
        for (int i = 0; i < 32; i++) asm volatile("" : "+v"(Wh[i]));
#pragma unroll
        for (int i = 0; i < 8; i++)  asm volatile("" : "+v"(Wx[i]));

        float bias[4];
#pragma unroll
        for (int nt = 0; nt < 4; nt++) {
            const int gr = nt * HID + s * 32 + myct * 16 + col;
            bias[nt] = bih0[gr] + bhh0[gr];
        }
        float cst[4] = {0, 0, 0, 0};

        for (int it = 0; it < SEQ; ++it) {
            // x prefetch (loads in flight during poll)
            f32x4 xr[4];
            if (w >= 2) {
#pragma unroll
                for (int m = 0; m < 2; m++) {
                    const float* px = x + ((size_t)(g * 32 + m * 16 + col) * SEQ + it) * DIN + (w - 2) * 32 + quad * 8;
                    xr[m * 2]     = *(const f32x4*)px;
                    xr[m * 2 + 1] = *(const f32x4*)(px + 4);
                }
            }
            if (w == 0 && it >= 1) {
                const unsigned nb = (it >= 8) ? (unsigned)(it - 7) : 0u;
                for (;;) {
                    unsigned v  = __hip_atomic_load(myf + lane, __ATOMIC_RELAXED, SCOPE_AGT);
                    unsigned b2 = __hip_atomic_load(bp,         __ATOMIC_RELAXED, SCOPE_AGT);
                    if (__all((int)((v >= (unsigned)it) & (b2 >= nb)))) break;
                    __builtin_amdgcn_s_sleep(1);
                }
            }
            __syncthreads();                            // A: gate + red-reuse guard

            f32x4 acc[16];
#pragma unroll
            for (int j = 0; j < 16; j++) acc[j] = (f32x4){0.f, 0.f, 0.f, 0.f};

            if (it > 0) {
                const f16_t* h0b = h0ring + (size_t)((it - 1) & 7) * BATCH * HID;
                f16x8 ab[8];                            // hoisted: batch under one drain
#pragma unroll
                for (int i = 0; i < 4; i++)
#pragma unroll
                    for (int m = 0; m < 2; m++)
                        ab[i * 2 + m] = ldx8(h0b + (size_t)(g * 32 + m * 16 + col) * HID
                                             + (w * 4 + i) * 32 + quad * 8);
#pragma unroll
                for (int i = 0; i < 4; i++)
#pragma unroll
                    for (int m = 0; m < 2; m++)
#pragma unroll
                        for (int ct = 0; ct < 2; ct++)
#pragma unroll
                            for (int nt = 0; nt < 4; nt++)
                                acc[m * 8 + ct * 4 + nt] = __builtin_amdgcn_mfma_f32_16x16x32_f16(
                                    ab[i * 2 + m], Wh[i * 8 + ct * 4 + nt], acc[m * 8 + ct * 4 + nt], 0, 0, 0);
            }
            if (w >= 2) {
#pragma unroll
                for (int m = 0; m < 2; m++) {
                    f16x8 a = cvt8v(xr[m * 2], xr[m * 2 + 1]);
#pragma unroll
                    for (int ct = 0; ct < 2; ct++)
#pragma unroll
                        for (int nt = 0; nt < 4; nt++)
                            acc[m * 8 + ct * 4 + nt] = __builtin_amdgcn_mfma_f32_16x16x32_f16(
                                a, Wx[ct * 4 + nt], acc[m * 8 + ct * 4 + nt], 0, 0, 0);
                }
            }
#pragma unroll
            for (int j = 0; j < 16; j++) red[w][j][lane] = acc[j];
            __syncthreads();                            // B: partials published

            // cell: wave (mym, myct) -> 16 rows x 16 dims
            f32x4 gate[4];
#pragma unroll
            for (int nt = 0; nt < 4; nt++) {
                f32x4 v = red[0][mym * 8 + myct * 4 + nt][lane];
#pragma unroll
                for (int ww = 1; ww < 4; ww++) {
                    f32x4 p = red[ww][mym * 8 + myct * 4 + nt][lane];
#pragma unroll
                    for (int r = 0; r < 4; r++) v[r] += p[r];
                }
                gate[nt] = v;
            }
            f16_t* hout = h0ring + (size_t)(it & 7) * BATCH * HID;
#pragma unroll
            for (int r = 0; r < 4; r++) {
                float iv = sgm(gate[0][r] + bias[0]), fv = sgm(gate[1][r] + bias[1]);
                float gv = th(gate[2][r] + bias[2]),  ov = sgm(gate[3][r] + bias[3]);
                float c = fv * cst[r] + iv * gv;
                cst[r] = c;
                float h = ov * th(c);
                float hn = __shfl_down(h, 1);
                if ((lane & 1) == 0)
                    sth2a(hout + (size_t)(g * 32 + mym * 16 + quad * 4 + r) * HID + s * 32 + myct * 16 + col, h, hn);
            }
            asm volatile("s_waitcnt vmcnt(0)" ::: "memory");   // own stores acked at IF$
            if (lane == 0)
                __hip_atomic_store(myf + s * 4 + mym * 2 + myct, (unsigned)(it + 1), __ATOMIC_RELAXED, SCOPE_AGT);
        }
    } else {
        // ============ L1 block: (G, s1) -- 64 rows x 16 dims ============
        const int idx = bid - 128;
        const int G = idx & 3, s1 = idx >> 2;          // s1 < 32
        unsigned* myf1 = f1 + G * 32;                  // flags [s1], value = it

        f16x8 Wb[32];
#pragma unroll
        for (int i = 0; i < 8; i++) {                  // kb = w*8+i over K=1024
            const int kb = w * 8 + i;
            const int k0 = kb * 32 + quad * 8;
#pragma unroll
            for (int nt = 0; nt < 4; nt++) {
                const int grow = nt * HID + s1 * 16 + col;
                const float* src = (kb < 16) ? (wih1 + (size_t)grow * HID + k0)
                                             : (whh1 + (size_t)grow * HID + (k0 - 512));
                Wb[i * 4 + nt] = cvt8(src);
            }
        }
#pragma unroll
        for (int i = 0; i < 32; i++) asm volatile("" : "+v"(Wb[i]));

        const int d = s1 * 16 + col;
        const float bi = bih1[d] + bhh1[d];
        const float bf = bih1[HID + d] + bhh1[HID + d];
        const float bg = bih1[2 * HID + d] + bhh1[2 * HID + d];
        const float bo = bih1[3 * HID + d] + bhh1[3 * HID + d];
        float cst[4] = {0, 0, 0, 0};

        for (int it = 1; it <= SEQ; ++it) {
            const int t = it - 1;
            if (w == 0) {
                const unsigned* pa = f0m + (2 * G) * 64;
                const unsigned* pb = f0m + (2 * G + 1) * 64;
                const bool chk = (it >= 2);
                for (;;) {
                    unsigned va = __hip_atomic_load(pa + lane, __ATOMIC_RELAXED, SCOPE_AGT);
                    unsigned vb = __hip_atomic_load(pb + lane, __ATOMIC_RELAXED, SCOPE_AGT);
                    unsigned vc = chk ? __hip_atomic_load(myf1 + (lane & 31), __ATOMIC_RELAXED, SCOPE_AGT)
                                      : 0xffffffffu;
                    if (__all((int)((va >= (unsigned)it) & (vb >= (unsigned)it) & (vc >= (unsigned)(it - 1))))) break;
                    __builtin_amdgcn_s_sleep(1);
                }
            }
            __syncthreads();                            // A

            f32x4 acc[16];
#pragma unroll
            for (int j = 0; j < 16; j++) acc[j] = (f32x4){0.f, 0.f, 0.f, 0.f};

            const f16_t* h0b = h0ring + (size_t)(t & 7) * BATCH * HID;
            const f16_t* h1r = h1buf + (size_t)((t - 1) & 1) * BATCH * HID;

            if (w < 2) {
                f16x8 ab[32];                           // hoisted batch (kb = w*8+i < 16)
#pragma unroll
                for (int i = 0; i < 8; i++)
#pragma unroll
                    for (int mt = 0; mt < 4; mt++)
                        ab[i * 4 + mt] = ldx8(h0b + (size_t)(G * 64 + mt * 16 + col) * HID
                                              + (w * 8 + i) * 32 + quad * 8);
#pragma unroll
                for (int i = 0; i < 8; i++)
#pragma unroll
                    for (int mt = 0; mt < 4; mt++)
#pragma unroll
                        for (int nt = 0; nt < 4; nt++)
                            acc[mt * 4 + nt] = __builtin_amdgcn_mfma_f32_16x16x32_f16(
                                ab[i * 4 + mt], Wb[i * 4 + nt], acc[mt * 4 + nt], 0, 0, 0);
            } else if (t > 0) {
                f16x8 ab[32];                           // kb = w*8+i >= 16 -> h1
#pragma unroll
                for (int i = 0; i < 8; i++)
#pragma unroll
                    for (int mt = 0; mt < 4; mt++)
                        ab[i * 4 + mt] = ldx8(h1r + (size_t)(G * 64 + mt * 16 + col) * HID
                                              + (w * 8 + i - 16) * 32 + quad * 8);
#pragma unroll
                for (int i = 0; i < 8; i++)
#pragma unroll
                    for (int mt = 0; mt < 4; mt++)
#pragma unroll
                        for (int nt = 0; nt < 4; nt++)
                            acc[mt * 4 + nt] = __builtin_amdgcn_mfma_f32_16x16x32_f16(
                                ab[i * 4 + mt], Wb[i * 4 + nt], acc[mt * 4 + nt], 0, 0, 0);
            }
#pragma unroll
            for (int j = 0; j < 16; j++) red[w][j][lane] = acc[j];
            __syncthreads();                            // B

            // cell: wave w = m-tile mt -> 16 rows x 16 dims
            f32x4 gate[4];
#pragma unroll
            for (int nt = 0; nt < 4; nt++) {
                f32x4 v = red[0][w * 4 + nt][lane];
#pragma unroll
                for (int ww = 1; ww < 4; ww++) {
                    f32x4 p = red[ww][w * 4 + nt][lane];
#pragma unroll
                    for (int r = 0; r < 4; r++) v[r] += p[r];
                }
                gate[nt] = v;
            }
            f16_t* hout = h1buf + (size_t)(t & 1) * BATCH * HID;
#pragma unroll
            for (int r = 0; r < 4; r++) {
                float iv = sgm(gate[0][r] + bi), fv = sgm(gate[1][r] + bf);
                float gv = th(gate[2][r] + bg),  ov = sgm(gate[3][r] + bo);
                float c = fv * cst[r] + iv * gv;
                cst[r] = c;
                float h = ov * th(c);
                float hn = __shfl_down(h, 1);
                if ((lane & 1) == 0)
                    sth2a(hout + (size_t)(G * 64 + w * 16 + quad * 4 + r) * HID + s1 * 16 + col, h, hn);
            }
            __syncthreads();                            // C: all waves' stores drained
            if (tid == 0)
                __hip_atomic_store(myf1 + s1, (unsigned)it, __ATOMIC_RELAXED, SCOPE_AGT);
        }
    }
}

// out[b] = dot(h1[511][b], fc_w) + fc_b ; slot = 511&1 = 1.
__global__ void fc_k(const f16_t* __restrict__ h1buf, const float* __restrict__ fcw,
                     const float* __restrict__ fcb, float* __restrict__ out)
{
    const int b = blockIdx.x, lane = threadIdx.x;
    const f16_t* hp = h1buf + ((size_t)(BATCH + b)) * HID;
    float sum = 0.f;
#pragma unroll
    for (int j = 0; j < 8; j++) {
        const int k = lane * 8 + j;
        sum += (float)hp[k] * fcw[k];
    }
#pragma unroll
    for (int off = 32; off; off >>= 1) sum += __shfl_down(sum, off);
    if (lane == 0) out[b] = sum + fcb[0];
}

extern "C" void kernel_launch(void* const* d_in, const int* in_sizes, int n_in,
                              void* d_out, int out_size, void* d_ws, size_t ws_size,
                              hipStream_t stream)
{
    const float* x    = (const float*)d_in[0];
    const float* wih0 = (const float*)d_in[1];
    const float* whh0 = (const float*)d_in[2];
    const float* bih0 = (const float*)d_in[3];
    const float* bhh0 = (const float*)d_in[4];
    const float* wih1 = (const float*)d_in[5];
    const float* whh1 = (const float*)d_in[6];
    const float* bih1 = (const float*)d_in[7];
    const float* bhh1 = (const float*)d_in[8];
    const float* fcw  = (const float*)d_in[9];
    const float* fcb  = (const float*)d_in[10];
    float* out = (float*)d_out;

    unsigned char* ws = (unsigned char*)d_ws;
    unsigned* f0m = (unsigned*)ws;                // 8 groups * 64 dwords = 2 KB
    unsigned* f1  = (unsigned*)(ws + 2048);       // 4 groups * 32 dwords = 512 B
    f16_t* h1buf  = (f16_t*)(ws + 4096);          // 2 slots * 256*512 f16 = 512 KB
    f16_t* h0ring = (f16_t*)(ws + 4096 + 2 * BATCH * HID * sizeof(f16_t));  // 8 slots = 2 MB

    hipMemsetAsync(ws, 0, 4096, stream);          // zero epoch flags
    lstm_pipe<<<dim3(256), dim3(256), 0, stream>>>(x, wih0, whh0, bih0, bhh0,
                                                   wih1, whh1, bih1, bhh1,
                                                   f0m, f1, h1buf, h0ring);
    fc_k<<<dim3(BATCH), dim3(64), 0, stream>>>(h1buf, fcw, fcb, out);
}

// Round 6
// 4469.875 us; speedup vs baseline: 1.2531x; 1.2531x over previous
//
#include <hip/hip_runtime.h>

// 2-layer LSTM (B=256,T=512,D=64,H=512) + FC(last step), MI355X gfx950.
// Round 14: R8 EXACT protocol (write-once 128MB h0 history, cached h0
// consumer loads, ldx8 h1 ping-pong, agent IF$ flags, wave-0-only polls,
// 2-barrier L0 / 3-barrier L1) + PREWARM RESCHEDULE:
//   R8 issued prewarm (4 cold-HBM agent loads) at step start and forced
//   completion via dependent-sum sink. vmcnt retires IN ISSUE ORDER =>
//   (a) wave 0's poll load could not retire before the cold fetches ->
//   flag discovery gated by HBM every step; (b) every wave stalled at the
//   sink pre-barrier-A. Fix: prefetch slot it+1, issued AFTER the last
//   consumed VMEM load of the step (post-MFMA), sunk lazily at the top of
//   the NEXT iteration (wait is free by then). Poll runs on a clean
//   counter; cold-allocate cost moves off the critical path.
//   Also: L1 fragment loads hoisted into 16-wide batches (one latency).
//   R12 lesson: polls stay wave-0-only. R13 lesson: keep cached write-once
//   reads + write-through stores; no sc0, no rings.

#define BATCH 256
#define SEQ   512
#define DIN   64
#define HID   512

typedef _Float16 f16_t;
typedef __attribute__((ext_vector_type(8))) _Float16 f16x8;
typedef __attribute__((ext_vector_type(4))) float    f32x4;

#define SCOPE_AGT __HIP_MEMORY_SCOPE_AGENT

__device__ inline f16x8 cvt8(const float* __restrict__ p) {
    f16x8 r;
#pragma unroll
    for (int j = 0; j < 8; j++) r[j] = (_Float16)p[j];
    return r;
}

__device__ inline f16x8 cvt8v(f32x4 lo, f32x4 hi) {
    f16x8 r;
#pragma unroll
    for (int j = 0; j < 4; j++) { r[j] = (_Float16)lo[j]; r[4 + j] = (_Float16)hi[j]; }
    return r;
}

// 16B coherence-point load (h1 slots; bypasses L1/L2 -> never stale).
__device__ inline f16x8 ldx8(const f16_t* p) {
    const unsigned long long* q = (const unsigned long long*)p;
    unsigned long long a = __hip_atomic_load(q,     __ATOMIC_RELAXED, SCOPE_AGT);
    unsigned long long b = __hip_atomic_load(q + 1, __ATOMIC_RELAXED, SCOPE_AGT);
    union { unsigned long long u[2]; f16x8 v; } c;
    c.u[0] = a; c.u[1] = b;
    return c.v;
}

// Coherent h-pair store (dword to IF$).
__device__ inline void sth2a(f16_t* base_even, float h, float hn) {
    union { struct { _Float16 lo, hi; } s; unsigned u; } pk;
    pk.s.lo = (_Float16)h; pk.s.hi = (_Float16)hn;
    __hip_atomic_store((unsigned*)base_even, pk.u, __ATOMIC_RELAXED, SCOPE_AGT);
}

// Poller wave: lane i watches p[i].
__device__ inline void pollw(const unsigned* p, unsigned need, int lane) {
    for (;;) {
        unsigned v = __hip_atomic_load(p + lane, __ATOMIC_RELAXED, SCOPE_AGT);
        if (__all((int)(v >= need))) break;
        __builtin_amdgcn_s_sleep(1);
    }
}

__device__ inline float sgm(float v) { return 1.f / (1.f + __expf(-v)); }
__device__ inline float th(float v)  { return 1.f - 2.f / (__expf(2.f * v) + 1.f); }

__global__ __launch_bounds__(256, 1) void lstm_pipe(
    const float* __restrict__ x,
    const float* __restrict__ wih0, const float* __restrict__ whh0,
    const float* __restrict__ bih0, const float* __restrict__ bhh0,
    const float* __restrict__ wih1, const float* __restrict__ whh1,
    const float* __restrict__ bih1, const float* __restrict__ bhh1,
    unsigned* __restrict__ f0m, unsigned* __restrict__ f1,
    f16_t* __restrict__ h1buf, f16_t* __restrict__ h0hist)
{
    // 87 KB: 2 blocks would need 174 KB > 160 KB -> guaranteed 1 block/CU.
    __shared__ f32x4 red[5][17][64];     // use [0..3][0..15][lane]

    const int tid  = threadIdx.x;
    const int w    = tid >> 6, lane = tid & 63;
    const int quad = lane >> 4, col = lane & 15;
    const int bid  = blockIdx.x;

    if (bid < 128) {
        // ============ L0 block: (g, s) -- 32 rows x 32 dims ============
        const int g = bid & 7, s = bid >> 3;           // s < 16
        unsigned* myf = f0m + g * 64;                  // flags [s*4+m*2+ct], val it+1
        const int mym = w & 1, myct = w >> 1;          // this wave's cell quarter

        f16x8 Wh[32];                                  // [i<4][ct<2][nt<4]
#pragma unroll
        for (int i = 0; i < 4; i++) {
            const int k0 = (w * 4 + i) * 32 + quad * 8;
#pragma unroll
            for (int ct = 0; ct < 2; ct++)
#pragma unroll
                for (int nt = 0; nt < 4; nt++) {
                    const int gr = nt * HID + s * 32 + ct * 16 + col;
                    Wh[i * 8 + ct * 4 + nt] = cvt8(whh0 + (size_t)gr * HID + k0);
                }
        }
        f16x8 Wx[8];
        if (w >= 2) {
#pragma unroll
            for (int ct = 0; ct < 2; ct++)
#pragma unroll
                for (int nt = 0; nt < 4; nt++) {
                    const int gr = nt * HID + s * 32 + ct * 16 + col;
                    Wx[ct * 4 + nt] = cvt8(wih0 + (size_t)gr * DIN + (w - 2) * 32 + quad * 8);
                }
        } else {
#pragma unroll
            for (int j = 0; j < 8; j++) Wx[j] = (f16x8)(_Float16)0;
        }
#pragma unroll
        for (int i = 0; i < 32; i++) asm volatile("" : "+v"(Wh[i]));
#pragma unroll
        for (int i = 0; i < 8; i++)  asm volatile("" : "+v"(Wx[i]));

        float bias[4];
#pragma unroll
        for (int nt = 0; nt < 4; nt++) {
            const int gr = nt * HID + s * 32 + myct * 16 + col;
            bias[nt] = bih0[gr] + bhh0[gr];
        }
        float cst[4] = {0, 0, 0, 0};
        unsigned pw0 = 0, pw1 = 0, pw2 = 0, pw3 = 0;   // lagged prewarm results

        for (int it = 0; it < SEQ; ++it) {
            // lazy sink of LAST step's prewarm loads (issued ~6us ago: free
            // wait) -- clears vmcnt so wave 0's poll is not HBM-gated.
            asm volatile("" : "+v"(pw0), "+v"(pw1), "+v"(pw2), "+v"(pw3));

            // x prefetch (loads in flight during poll)
            f32x4 xr[4];
            if (w >= 2) {
#pragma unroll
                for (int m = 0; m < 2; m++) {
                    const float* px = x + ((size_t)(g * 32 + m * 16 + col) * SEQ + it) * DIN + (w - 2) * 32 + quad * 8;
                    xr[m * 2]     = *(const f32x4*)px;
                    xr[m * 2 + 1] = *(const f32x4*)(px + 4);
                }
            }
            if (w == 0 && it >= 1) pollw(myf, (unsigned)it, lane);
            __syncthreads();                            // A: gate + red-reuse guard

            f32x4 acc[16];
#pragma unroll
            for (int j = 0; j < 16; j++) acc[j] = (f32x4){0.f, 0.f, 0.f, 0.f};

            if (it > 0) {
                const f16_t* h0b = h0hist + (size_t)(it - 1) * BATCH * HID;   // write-once: cached loads
                f16x8 ab[8];
#pragma unroll
                for (int i = 0; i < 4; i++)
#pragma unroll
                    for (int m = 0; m < 2; m++)
                        ab[i * 2 + m] = *(const f16x8*)(h0b + (size_t)(g * 32 + m * 16 + col) * HID
                                                        + (w * 4 + i) * 32 + quad * 8);
#pragma unroll
                for (int i = 0; i < 4; i++)
#pragma unroll
                    for (int m = 0; m < 2; m++)
#pragma unroll
                        for (int ct = 0; ct < 2; ct++)
#pragma unroll
                            for (int nt = 0; nt < 4; nt++)
                                acc[m * 8 + ct * 4 + nt] = __builtin_amdgcn_mfma_f32_16x16x32_f16(
                                    ab[i * 2 + m], Wh[i * 8 + ct * 4 + nt], acc[m * 8 + ct * 4 + nt], 0, 0, 0);
            }
            if (w >= 2) {
#pragma unroll
                for (int m = 0; m < 2; m++) {
                    f16x8 a = cvt8v(xr[m * 2], xr[m * 2 + 1]);
#pragma unroll
                    for (int ct = 0; ct < 2; ct++)
#pragma unroll
                        for (int nt = 0; nt < 4; nt++)
                            acc[m * 8 + ct * 4 + nt] = __builtin_amdgcn_mfma_f32_16x16x32_f16(
                                a, Wx[ct * 4 + nt], acc[m * 8 + ct * 4 + nt], 0, 0, 0);
                }
            }

            // prewarm NEXT step's store lines (slot it+1) into IF$.
            // Issued after the last consumed VMEM load of this step: nothing
            // waits on these until the end-of-step drain (~2-3us later), and
            // the lazy sink next iteration is free. No store-allocate from
            // cold HBM on the producer path; poll stays clean.
            if (it + 1 < SEQ) {
                const f16_t* hw = h0hist + (size_t)(it + 1) * BATCH * HID;
                const f16_t* rw = hw + (size_t)(g * 32 + mym * 16 + quad * 4) * HID
                                     + s * 32 + myct * 16 + (col & ~1);
                pw0 = __hip_atomic_load((const unsigned*)(rw),            __ATOMIC_RELAXED, SCOPE_AGT);
                pw1 = __hip_atomic_load((const unsigned*)(rw + HID),      __ATOMIC_RELAXED, SCOPE_AGT);
                pw2 = __hip_atomic_load((const unsigned*)(rw + 2 * HID),  __ATOMIC_RELAXED, SCOPE_AGT);
                pw3 = __hip_atomic_load((const unsigned*)(rw + 3 * HID),  __ATOMIC_RELAXED, SCOPE_AGT);
            }

#pragma unroll
            for (int j = 0; j < 16; j++) red[w][j][lane] = acc[j];
            __syncthreads();                            // B: partials published

            // cell: wave (mym, myct) -> 16 rows x 16 dims
            f32x4 gate[4];
#pragma unroll
            for (int nt = 0; nt < 4; nt++) {
                f32x4 v = red[0][mym * 8 + myct * 4 + nt][lane];
#pragma unroll
                for (int ww = 1; ww < 4; ww++) {
                    f32x4 p = red[ww][mym * 8 + myct * 4 + nt][lane];
#pragma unroll
                    for (int r = 0; r < 4; r++) v[r] += p[r];
                }
                gate[nt] = v;
            }
            f16_t* hout = h0hist + (size_t)it * BATCH * HID;
#pragma unroll
            for (int r = 0; r < 4; r++) {
                float iv = sgm(gate[0][r] + bias[0]), fv = sgm(gate[1][r] + bias[1]);
                float gv = th(gate[2][r] + bias[2]),  ov = sgm(gate[3][r] + bias[3]);
                float c = fv * cst[r] + iv * gv;
                cst[r] = c;
                float h = ov * th(c);
                float hn = __shfl_down(h, 1);
                if ((lane & 1) == 0)
                    sth2a(hout + (size_t)(g * 32 + mym * 16 + quad * 4 + r) * HID + s * 32 + myct * 16 + col, h, hn);
            }
            asm volatile("s_waitcnt vmcnt(0)" ::: "memory");   // own stores acked at IF$
            if (lane == 0)
                __hip_atomic_store(myf + s * 4 + mym * 2 + myct, (unsigned)(it + 1), __ATOMIC_RELAXED, SCOPE_AGT);
        }
    } else {
        // ============ L1 block: (G, s1) -- 64 rows x 16 dims ============
        const int idx = bid - 128;
        const int G = idx & 3, s1 = idx >> 2;          // s1 < 32
        unsigned* myf1 = f1 + G * 32;                  // flags [s1], value = it

        f16x8 Wb[32];
#pragma unroll
        for (int i = 0; i < 8; i++) {                  // kb = w*8+i over K=1024
            const int kb = w * 8 + i;
            const int k0 = kb * 32 + quad * 8;
#pragma unroll
            for (int nt = 0; nt < 4; nt++) {
                const int grow = nt * HID + s1 * 16 + col;
                const float* src = (kb < 16) ? (wih1 + (size_t)grow * HID + k0)
                                             : (whh1 + (size_t)grow * HID + (k0 - 512));
                Wb[i * 4 + nt] = cvt8(src);
            }
        }
#pragma unroll
        for (int i = 0; i < 32; i++) asm volatile("" : "+v"(Wb[i]));

        const int d = s1 * 16 + col;
        const float bi = bih1[d] + bhh1[d];
        const float bf = bih1[HID + d] + bhh1[HID + d];
        const float bg = bih1[2 * HID + d] + bhh1[2 * HID + d];
        const float bo = bih1[3 * HID + d] + bhh1[3 * HID + d];
        float cst[4] = {0, 0, 0, 0};

        for (int it = 1; it <= SEQ; ++it) {
            const int t = it - 1;
            if (w == 0) {
                const unsigned* pa = f0m + (2 * G) * 64;
                const unsigned* pb = f0m + (2 * G + 1) * 64;
                const bool chk = (it >= 2);
                for (;;) {
                    unsigned va = __hip_atomic_load(pa + lane, __ATOMIC_RELAXED, SCOPE_AGT);
                    unsigned vb = __hip_atomic_load(pb + lane, __ATOMIC_RELAXED, SCOPE_AGT);
                    unsigned vc = chk ? __hip_atomic_load(myf1 + (lane & 31), __ATOMIC_RELAXED, SCOPE_AGT)
                                      : 0xffffffffu;
                    if (__all((int)((va >= (unsigned)it) & (vb >= (unsigned)it) & (vc >= (unsigned)(it - 1))))) break;
                    __builtin_amdgcn_s_sleep(1);
                }
            }
            __syncthreads();                            // A

            f32x4 acc[16];
#pragma unroll
            for (int j = 0; j < 16; j++) acc[j] = (f32x4){0.f, 0.f, 0.f, 0.f};

            const f16_t* h0b = h0hist + (size_t)t * BATCH * HID;   // cached, write-once
            const f16_t* h1r = h1buf + (size_t)((t - 1) & 1) * BATCH * HID;

            if (w < 2) {
                // two half-batches of 16 cached loads (one latency each)
#pragma unroll
                for (int half = 0; half < 2; half++) {
                    f16x8 ab[16];
#pragma unroll
                    for (int i = 0; i < 4; i++)
#pragma unroll
                        for (int mt = 0; mt < 4; mt++)
                            ab[i * 4 + mt] = *(const f16x8*)(h0b + (size_t)(G * 64 + mt * 16 + col) * HID
                                                             + (w * 8 + half * 4 + i) * 32 + quad * 8);
#pragma unroll
                    for (int i = 0; i < 4; i++)
#pragma unroll
                        for (int mt = 0; mt < 4; mt++)
#pragma unroll
                            for (int nt = 0; nt < 4; nt++)
                                acc[mt * 4 + nt] = __builtin_amdgcn_mfma_f32_16x16x32_f16(
                                    ab[i * 4 + mt], Wb[(half * 4 + i) * 4 + nt], acc[mt * 4 + nt], 0, 0, 0);
                }
            } else if (t > 0) {
#pragma unroll
                for (int half = 0; half < 2; half++) {
                    f16x8 ab[16];
#pragma unroll
                    for (int i = 0; i < 4; i++)
#pragma unroll
                        for (int mt = 0; mt < 4; mt++)
                            ab[i * 4 + mt] = ldx8(h1r + (size_t)(G * 64 + mt * 16 + col) * HID
                                                  + (w * 8 + half * 4 + i - 16) * 32 + quad * 8);
#pragma unroll
                    for (int i = 0; i < 4; i++)
#pragma unroll
                        for (int mt = 0; mt < 4; mt++)
#pragma unroll
                            for (int nt = 0; nt < 4; nt++)
                                acc[mt * 4 + nt] = __builtin_amdgcn_mfma_f32_16x16x32_f16(
                                    ab[i * 4 + mt], Wb[(half * 4 + i) * 4 + nt], acc[mt * 4 + nt], 0, 0, 0);
                }
            }
#pragma unroll
            for (int j = 0; j < 16; j++) red[w][j][lane] = acc[j];
            __syncthreads();                            // B

            // cell: wave w = m-tile mt -> 16 rows x 16 dims
            f32x4 gate[4];
#pragma unroll
            for (int nt = 0; nt < 4; nt++) {
                f32x4 v = red[0][w * 4 + nt][lane];
#pragma unroll
                for (int ww = 1; ww < 4; ww++) {
                    f32x4 p = red[ww][w * 4 + nt][lane];
#pragma unroll
                    for (int r = 0; r < 4; r++) v[r] += p[r];
                }
                gate[nt] = v;
            }
            f16_t* hout = h1buf + (size_t)(t & 1) * BATCH * HID;
#pragma unroll
            for (int r = 0; r < 4; r++) {
                float iv = sgm(gate[0][r] + bi), fv = sgm(gate[1][r] + bf);
                float gv = th(gate[2][r] + bg),  ov = sgm(gate[3][r] + bo);
                float c = fv * cst[r] + iv * gv;
                cst[r] = c;
                float h = ov * th(c);
                float hn = __shfl_down(h, 1);
                if ((lane & 1) == 0)
                    sth2a(hout + (size_t)(G * 64 + w * 16 + quad * 4 + r) * HID + s1 * 16 + col, h, hn);
            }
            __syncthreads();                            // C: all waves' stores drained
            if (tid == 0)
                __hip_atomic_store(myf1 + s1, (unsigned)it, __ATOMIC_RELAXED, SCOPE_AGT);
        }
    }
}

// out[b] = dot(h1[511][b], fc_w) + fc_b ; slot = 511&1 = 1.
__global__ void fc_k(const f16_t* __restrict__ h1buf, const float* __restrict__ fcw,
                     const float* __restrict__ fcb, float* __restrict__ out)
{
    const int b = blockIdx.x, lane = threadIdx.x;
    const f16_t* hp = h1buf + ((size_t)(BATCH + b)) * HID;
    float sum = 0.f;
#pragma unroll
    for (int j = 0; j < 8; j++) {
        const int k = lane * 8 + j;
        sum += (float)hp[k] * fcw[k];
    }
#pragma unroll
    for (int off = 32; off; off >>= 1) sum += __shfl_down(sum, off);
    if (lane == 0) out[b] = sum + fcb[0];
}

extern "C" void kernel_launch(void* const* d_in, const int* in_sizes, int n_in,
                              void* d_out, int out_size, void* d_ws, size_t ws_size,
                              hipStream_t stream)
{
    const float* x    = (const float*)d_in[0];
    const float* wih0 = (const float*)d_in[1];
    const float* whh0 = (const float*)d_in[2];
    const float* bih0 = (const float*)d_in[3];
    const float* bhh0 = (const float*)d_in[4];
    const float* wih1 = (const float*)d_in[5];
    const float* whh1 = (const float*)d_in[6];
    const float* bih1 = (const float*)d_in[7];
    const float* bhh1 = (const float*)d_in[8];
    const float* fcw  = (const float*)d_in[9];
    const float* fcb  = (const float*)d_in[10];
    float* out = (float*)d_out;

    unsigned char* ws = (unsigned char*)d_ws;
    unsigned* f0m = (unsigned*)ws;                // 8 groups * 64 dwords = 2 KB
    unsigned* f1  = (unsigned*)(ws + 2048);       // 4 groups * 32 dwords = 512 B
    f16_t* h1buf  = (f16_t*)(ws + 4096);          // 2 slots * 256*512 f16 = 512 KB
    f16_t* h0hist = (f16_t*)(ws + 4096 + 2 * BATCH * HID * sizeof(f16_t));  // 128 MB

    hipMemsetAsync(ws, 0, 4096, stream);          // zero epoch flags
    lstm_pipe<<<dim3(256), dim3(256), 0, stream>>>(x, wih0, whh0, bih0, bhh0,
                                                   wih1, whh1, bih1, bhh1,
                                                   f0m, f1, h1buf, h0hist);
    fc_k<<<dim3(BATCH), dim3(64), 0, stream>>>(h1buf, fcw, fcb, out);
}